// Round 5
// baseline (122.975 us; speedup 1.0000x reference)
//
#include <hip/hip_runtime.h>

#define DIM 16
#define K_TOK 16   // tokens per 16-lane stream; fully unrolled

typedef int   vi4 __attribute__((ext_vector_type(4)));
typedef float vf4 __attribute__((ext_vector_type(4)));

// out[b*DIM + d] = bias[d], vectorized float4 (d_out poisoned to 0xAA pre-launch)
__global__ void init_out_kernel(float4* __restrict__ out4,
                                const float* __restrict__ bias,
                                int n4) {
    int i = blockIdx.x * blockDim.x + threadIdx.x;
    if (i < n4) {
        int d = (i & 3) * 4;   // DIM=16 -> 4 float4 per row
        out4[i] = make_float4(bias[d], bias[d + 1], bias[d + 2], bias[d + 3]);
    }
}

// 16 lanes per stream (lane = dim), 16 consecutive tokens per stream.
// All index/rating/seg data loaded as non-temporal dwordx4 (read-once
// streams), all 16 weight-row gathers issued non-temporally (row reuse
// ~1.3x, 64MB table >> L2 -> allocation is pure churn) before any use.
// Sorted segment_ids -> register run-length accumulate; atomicAdd only at
// segment boundaries.
__global__ __launch_bounds__(256) void features_linear_kernel(
    const int*   __restrict__ ids,
    const float* __restrict__ ratings,
    const int*   __restrict__ segs,
    const float* __restrict__ weight,
    float*       __restrict__ out,
    int total) {
    int tid = blockIdx.x * blockDim.x + threadIdx.x;
    int d = tid & (DIM - 1);
    int stream_id = tid >> 4;
    int t0 = stream_id * K_TOK;
    if (t0 >= total) return;

    float acc = 0.0f;
    int prev = segs[t0];

    if (t0 + K_TOK <= total) {
        const vi4* idv = (const vi4*)(ids + t0);
        const vf4* rv  = (const vf4*)(ratings + t0);
        const vi4* sv  = (const vi4*)(segs + t0);

        vi4 id0 = __builtin_nontemporal_load(idv + 0);
        vi4 id1 = __builtin_nontemporal_load(idv + 1);
        vi4 id2 = __builtin_nontemporal_load(idv + 2);
        vi4 id3 = __builtin_nontemporal_load(idv + 3);
        vf4 r0  = __builtin_nontemporal_load(rv + 0);
        vf4 r1  = __builtin_nontemporal_load(rv + 1);
        vf4 r2  = __builtin_nontemporal_load(rv + 2);
        vf4 r3  = __builtin_nontemporal_load(rv + 3);
        vi4 s0  = __builtin_nontemporal_load(sv + 0);
        vi4 s1  = __builtin_nontemporal_load(sv + 1);
        vi4 s2  = __builtin_nontemporal_load(sv + 2);
        vi4 s3  = __builtin_nontemporal_load(sv + 3);

        #define WLOAD(idx_) __builtin_nontemporal_load(&weight[(size_t)(idx_) * DIM + d])
        float w0  = WLOAD(id0.x);
        float w1  = WLOAD(id0.y);
        float w2  = WLOAD(id0.z);
        float w3  = WLOAD(id0.w);
        float w4  = WLOAD(id1.x);
        float w5  = WLOAD(id1.y);
        float w6  = WLOAD(id1.z);
        float w7  = WLOAD(id1.w);
        float w8  = WLOAD(id2.x);
        float w9  = WLOAD(id2.y);
        float w10 = WLOAD(id2.z);
        float w11 = WLOAD(id2.w);
        float w12 = WLOAD(id3.x);
        float w13 = WLOAD(id3.y);
        float w14 = WLOAD(id3.z);
        float w15 = WLOAD(id3.w);
        #undef WLOAD

        #define STEP(sv_, wv_, rv_)                                        \
            if ((sv_) != prev) {                                           \
                atomicAdd(&out[prev * DIM + d], acc);                      \
                acc = 0.0f; prev = (sv_);                                  \
            }                                                              \
            acc = fmaf((wv_), (rv_), acc);

        STEP(s0.x, w0,  r0.x)  STEP(s0.y, w1,  r0.y)
        STEP(s0.z, w2,  r0.z)  STEP(s0.w, w3,  r0.w)
        STEP(s1.x, w4,  r1.x)  STEP(s1.y, w5,  r1.y)
        STEP(s1.z, w6,  r1.z)  STEP(s1.w, w7,  r1.w)
        STEP(s2.x, w8,  r2.x)  STEP(s2.y, w9,  r2.y)
        STEP(s2.z, w10, r2.z)  STEP(s2.w, w11, r2.w)
        STEP(s3.x, w12, r3.x)  STEP(s3.y, w13, r3.y)
        STEP(s3.z, w14, r3.z)  STEP(s3.w, w15, r3.w)
        #undef STEP
    } else {
        for (int t = t0; t < total; ++t) {
            int seg = segs[t];
            if (seg != prev) {
                atomicAdd(&out[prev * DIM + d], acc);
                acc = 0.0f;
                prev = seg;
            }
            acc = fmaf(weight[(size_t)ids[t] * DIM + d], ratings[t], acc);
        }
    }
    atomicAdd(&out[prev * DIM + d], acc);
}

extern "C" void kernel_launch(void* const* d_in, const int* in_sizes, int n_in,
                              void* d_out, int out_size, void* d_ws, size_t ws_size,
                              hipStream_t stream) {
    const int*   ids     = (const int*)d_in[0];
    const float* ratings = (const float*)d_in[1];
    const int*   segs    = (const int*)d_in[2];
    // d_in[3] = batch_size scalar (unused; batch = out_size / DIM)
    const float* weight  = (const float*)d_in[4];
    const float* bias    = (const float*)d_in[5];
    float* out = (float*)d_out;

    int total = in_sizes[0];

    // 1) initialize output with bias (vectorized)
    {
        int n4 = out_size / 4;
        int threads = 256;
        int blocks = (n4 + threads - 1) / threads;
        init_out_kernel<<<blocks, threads, 0, stream>>>((float4*)out, bias, n4);
    }

    // 2) gather + segmented sum
    {
        int n_streams = (total + K_TOK - 1) / K_TOK;
        long long n_threads = (long long)n_streams * DIM;
        int threads = 256;
        int blocks = (int)((n_threads + threads - 1) / threads);
        features_linear_kernel<<<blocks, threads, 0, stream>>>(
            ids, ratings, segs, weight, out, total);
    }
}

// Round 6
// 115.592 us; speedup vs baseline: 1.0639x; 1.0639x over previous
//
#include <hip/hip_runtime.h>

#define DIM 16
#define K_TOK 16   // tokens per 16-lane stream; fully unrolled

// out[b*DIM + d] = bias[d], vectorized float4 (d_out poisoned to 0xAA pre-launch)
__global__ void init_out_kernel(float4* __restrict__ out4,
                                const float* __restrict__ bias,
                                int n4) {
    int i = blockIdx.x * blockDim.x + threadIdx.x;
    if (i < n4) {
        int d = (i & 3) * 4;   // DIM=16 -> 4 float4 per row
        out4[i] = make_float4(bias[d], bias[d + 1], bias[d + 2], bias[d + 3]);
    }
}

// 16 lanes per stream (lane = dim), 16 consecutive tokens per stream.
// Index/rating/seg data loaded as dwordx4, all 16 weight-row gathers issued
// before any use (16 lanes x dword = one coalesced 64B line per row).
// Sorted segment_ids -> register run-length accumulate; atomicAdd only at
// segment boundaries (~1.3 flushes/stream).
// NOTE (R5): __builtin_nontemporal_load on the gathers REGRESSED (+6us) --
// the ~1.46x row reuse needs L2 capture. Keep plain loads.
__global__ __launch_bounds__(256) void features_linear_kernel(
    const int*   __restrict__ ids,
    const float* __restrict__ ratings,
    const int*   __restrict__ segs,
    const float* __restrict__ weight,
    float*       __restrict__ out,
    int total) {
    int tid = blockIdx.x * blockDim.x + threadIdx.x;
    int d = tid & (DIM - 1);
    int stream_id = tid >> 4;
    int t0 = stream_id * K_TOK;
    if (t0 >= total) return;

    float acc = 0.0f;
    int prev = segs[t0];

    if (t0 + K_TOK <= total) {
        const int4*   idv = (const int4*)(ids + t0);
        const float4* rv  = (const float4*)(ratings + t0);
        const int4*   sv  = (const int4*)(segs + t0);

        int4   id0 = idv[0], id1 = idv[1], id2 = idv[2], id3 = idv[3];
        float4 r0  = rv[0],  r1  = rv[1],  r2  = rv[2],  r3  = rv[3];
        int4   s0  = sv[0],  s1  = sv[1],  s2  = sv[2],  s3  = sv[3];

        float w0  = weight[(size_t)id0.x * DIM + d];
        float w1  = weight[(size_t)id0.y * DIM + d];
        float w2  = weight[(size_t)id0.z * DIM + d];
        float w3  = weight[(size_t)id0.w * DIM + d];
        float w4  = weight[(size_t)id1.x * DIM + d];
        float w5  = weight[(size_t)id1.y * DIM + d];
        float w6  = weight[(size_t)id1.z * DIM + d];
        float w7  = weight[(size_t)id1.w * DIM + d];
        float w8  = weight[(size_t)id2.x * DIM + d];
        float w9  = weight[(size_t)id2.y * DIM + d];
        float w10 = weight[(size_t)id2.z * DIM + d];
        float w11 = weight[(size_t)id2.w * DIM + d];
        float w12 = weight[(size_t)id3.x * DIM + d];
        float w13 = weight[(size_t)id3.y * DIM + d];
        float w14 = weight[(size_t)id3.z * DIM + d];
        float w15 = weight[(size_t)id3.w * DIM + d];

        #define STEP(sv_, wv_, rv_)                                        \
            if ((sv_) != prev) {                                           \
                atomicAdd(&out[prev * DIM + d], acc);                      \
                acc = 0.0f; prev = (sv_);                                  \
            }                                                              \
            acc = fmaf((wv_), (rv_), acc);

        STEP(s0.x, w0,  r0.x)  STEP(s0.y, w1,  r0.y)
        STEP(s0.z, w2,  r0.z)  STEP(s0.w, w3,  r0.w)
        STEP(s1.x, w4,  r1.x)  STEP(s1.y, w5,  r1.y)
        STEP(s1.z, w6,  r1.z)  STEP(s1.w, w7,  r1.w)
        STEP(s2.x, w8,  r2.x)  STEP(s2.y, w9,  r2.y)
        STEP(s2.z, w10, r2.z)  STEP(s2.w, w11, r2.w)
        STEP(s3.x, w12, r3.x)  STEP(s3.y, w13, r3.y)
        STEP(s3.z, w14, r3.z)  STEP(s3.w, w15, r3.w)
        #undef STEP
    } else {
        for (int t = t0; t < total; ++t) {
            int seg = segs[t];
            if (seg != prev) {
                atomicAdd(&out[prev * DIM + d], acc);
                acc = 0.0f;
                prev = seg;
            }
            acc = fmaf(weight[(size_t)ids[t] * DIM + d], ratings[t], acc);
        }
    }
    atomicAdd(&out[prev * DIM + d], acc);
}

extern "C" void kernel_launch(void* const* d_in, const int* in_sizes, int n_in,
                              void* d_out, int out_size, void* d_ws, size_t ws_size,
                              hipStream_t stream) {
    const int*   ids     = (const int*)d_in[0];
    const float* ratings = (const float*)d_in[1];
    const int*   segs    = (const int*)d_in[2];
    // d_in[3] = batch_size scalar (unused; batch = out_size / DIM)
    const float* weight  = (const float*)d_in[4];
    const float* bias    = (const float*)d_in[5];
    float* out = (float*)d_out;

    int total = in_sizes[0];

    // 1) initialize output with bias (vectorized)
    {
        int n4 = out_size / 4;
        int threads = 256;
        int blocks = (n4 + threads - 1) / threads;
        init_out_kernel<<<blocks, threads, 0, stream>>>((float4*)out, bias, n4);
    }

    // 2) gather + segmented sum
    {
        int n_streams = (total + K_TOK - 1) / K_TOK;
        long long n_threads = (long long)n_streams * DIM;
        int threads = 256;
        int blocks = (int)((n_threads + threads - 1) / threads);
        features_linear_kernel<<<blocks, threads, 0, stream>>>(
            ids, ratings, segs, weight, out, total);
    }
}